// Round 20
// baseline (690.465 us; speedup 1.0000x reference)
//
#include <hip/hip_runtime.h>
#include <hip/hip_bf16.h>

#define DEV __device__ __forceinline__

typedef unsigned short u16;
typedef unsigned int u32;
typedef __attribute__((ext_vector_type(8))) short short8;
typedef __attribute__((ext_vector_type(4))) float f32x4;
typedef __attribute__((ext_vector_type(16))) float f32x16;

static constexpr int Bb = 2, Ss = 2048, Hh = 4096, NQ = 32, NKV = 8, Dd = 128;
static constexpr int Mm = Bb * Ss; // 4096

DEV u16 f2bf(float f) {
    u32 u = __float_as_uint(f);
    u32 r = (u + 0x7fffu + ((u >> 16) & 1u)) >> 16;
    return (u16)r;
}
DEV float bf2f(u16 b) { return __uint_as_float((u32)b << 16); }
DEV u32 cvtpk(float lo, float hi) { // dst.lo=bf16(lo), dst.hi=bf16(hi)
    u32 r;
    asm("v_cvt_pk_bf16_f32 %0, %1, %2" : "=v"(r) : "v"(lo), "v"(hi));
    return r;
}

// ---------------- elementwise f32 -> bf16 cast ----------------
__global__ void k_cast(const float4* __restrict__ in, ushort4* __restrict__ out, int n4) {
    int i = blockIdx.x * 256 + threadIdx.x;
    if (i < n4) {
        float4 v = in[i];
        ushort4 o;
        o.x = f2bf(v.x); o.y = f2bf(v.y); o.z = f2bf(v.z); o.w = f2bf(v.w);
        out[i] = o;
    }
}

// ---------------- transpose + cast: in (R,C) f32 -> out (C,R) bf16 ----------------
// 64x64 tile, 256 threads (16x16). float4 reads, bf16 into LDS transposed, ushort4 writes.
__global__ __launch_bounds__(256) void k_transpose(const float* __restrict__ in, u16* __restrict__ out,
                                                   int R, int C) {
    __shared__ u16 t[64][68];
    int tx = threadIdx.x & 15, ty = threadIdx.x >> 4; // 16 x 16
    long tr = (long)blockIdx.y * 64, tc = (long)blockIdx.x * 64;
    #pragma unroll
    for (int j = 0; j < 4; j++) {
        int r = ty + j * 16;
        float4 v = *(const float4*)&in[(tr + r) * C + tc + tx * 4];
        t[tx * 4 + 0][r] = f2bf(v.x);
        t[tx * 4 + 1][r] = f2bf(v.y);
        t[tx * 4 + 2][r] = f2bf(v.z);
        t[tx * 4 + 3][r] = f2bf(v.w);
    }
    __syncthreads();
    #pragma unroll
    for (int j = 0; j < 4; j++) {
        int c = ty + j * 16;
        *(ushort4*)&out[(tc + c) * R + tr + tx * 4] = *(ushort4*)&t[c][tx * 4];
    }
}

DEV void gld16(const void* g, void* l) {
    __builtin_amdgcn_global_load_lds((const __attribute__((address_space(1))) void*)g,
                                     (__attribute__((address_space(3))) void*)l, 16, 0, 0);
}

#define FENCE asm volatile("" ::: "memory")

// ---------------- 256xNW-tile 8-wave GEMM, minimum 2-phase K-loop ----------------
// ONE vmcnt(0) + ONE s_barrier per K-tile (round-16/18 proven best).
// MFMA de-paired: all k-half-0 MFMAs for all (m,n), then all k-half-1 — 23 independent
// ops between the two accumulations into each acc[m][n] (kills dependent-MFMA stalls).
// MODE 0: f32 C0 row-major (ld=N), N-tile 256 (NF=4) -> 256 blocks (1 generation).
// MODE 3: fused QKV, N-tile 192 (NF=3) -> 512 blocks (2 exact generations).
template <int MODE>
__global__ __launch_bounds__(512) void k_gemm256(const u16* __restrict__ A, const u16* __restrict__ B0,
                                                 void* __restrict__ C0, void* __restrict__ C1,
                                                 void* __restrict__ C2, int M, int N, int K, int nbx) {
    constexpr int NF = (MODE == 3) ? 3 : 4;     // n-frags per wave
    __shared__ u16 S[2][16384 + NF * 4096];
    const int tid = threadIdx.x, lane = tid & 63, wid = tid >> 6;
    const int wr = wid >> 2, wc = wid & 3;
    const int l = blockIdx.x;
    const int bx = l % nbx, by = l / nbx;
    const long m0 = (long)by * 256, n0 = (long)bx * (NF * 64);
    const int r15 = lane & 15;
    const int cch0 = 8 * ((lane >> 4) ^ (r15 & 7));

    const u16 *pA[4], *pB[NF];
    {
        int rl = lane >> 3;                      // row within 1KB issue
        int sc = 8 * ((lane & 7) ^ rl);          // pre-swizzled chunk
        #pragma unroll
        for (int j = 0; j < 4; j++)
            pA[j] = A + (m0 + (wid * 4 + j) * 8 + rl) * (long)K + sc;
        #pragma unroll
        for (int j = 0; j < NF; j++)
            pB[j] = B0 + (n0 + (wid * NF + j) * 8 + rl) * (long)K + sc;
    }

    f32x4 acc[8][NF];
    #pragma unroll
    for (int i = 0; i < 8; i++)
        #pragma unroll
        for (int j = 0; j < NF; j++) acc[i][j] = f32x4{0.f, 0.f, 0.f, 0.f};

    const int NT = K / 64;
    auto STAGE = [&](int t) {
        int tb = t & 1; long ko = (long)t * 64;
        #pragma unroll
        for (int j = 0; j < NF; j++) gld16(pB[j] + ko, (void*)&S[tb][16384 + (wid * NF + j) * 512]);
        #pragma unroll
        for (int j = 0; j < 4; j++) gld16(pA[j] + ko, (void*)&S[tb][(wid * 4 + j) * 512]);
    };

    const int aro = wr * 8192 + r15 * 64 + cch0;
    const int bro = 16384 + wc * (NF * 1024) + r15 * 64 + cch0;

    // prologue: stage tile 0, drain, sync
    STAGE(0);
    asm volatile("s_waitcnt vmcnt(0)" ::: "memory");
    FENCE; __builtin_amdgcn_s_barrier(); FENCE;

    short8 af[4][2], bf[NF][2];
    for (int kt = 0; kt < NT; ++kt) {
        const u16* Sb = S[kt & 1];
        // issue next-tile loads FIRST (they fly across this tile's compute)
        if (kt + 1 < NT) STAGE(kt + 1);
        // ---- reads B + A-mh0; MFMA (mh0 x all n), k-half passes separated
        #pragma unroll
        for (int n = 0; n < NF; n++) {
            bf[n][0] = *(const short8*)&Sb[bro + n * 1024];
            bf[n][1] = *(const short8*)&Sb[(bro + n * 1024) ^ 32];
        }
        #pragma unroll
        for (int m = 0; m < 4; m++) {
            af[m][0] = *(const short8*)&Sb[aro + m * 1024];
            af[m][1] = *(const short8*)&Sb[(aro + m * 1024) ^ 32];
        }
        __builtin_amdgcn_s_setprio(1);
        #pragma unroll
        for (int m = 0; m < 4; m++)
            #pragma unroll
            for (int n = 0; n < NF; n++)
                acc[m][n] = __builtin_amdgcn_mfma_f32_16x16x32_bf16(af[m][0], bf[n][0], acc[m][n], 0, 0, 0);
        #pragma unroll
        for (int m = 0; m < 4; m++)
            #pragma unroll
            for (int n = 0; n < NF; n++)
                acc[m][n] = __builtin_amdgcn_mfma_f32_16x16x32_bf16(af[m][1], bf[n][1], acc[m][n], 0, 0, 0);
        __builtin_amdgcn_s_setprio(0);
        // ---- reads A-mh1; MFMA (mh1 x all n), k-half passes separated
        short8 ag[4][2];
        #pragma unroll
        for (int m = 0; m < 4; m++) {
            ag[m][0] = *(const short8*)&Sb[aro + (m + 4) * 1024];
            ag[m][1] = *(const short8*)&Sb[(aro + (m + 4) * 1024) ^ 32];
        }
        __builtin_amdgcn_s_setprio(1);
        #pragma unroll
        for (int m = 0; m < 4; m++)
            #pragma unroll
            for (int n = 0; n < NF; n++)
                acc[m + 4][n] = __builtin_amdgcn_mfma_f32_16x16x32_bf16(ag[m][0], bf[n][0], acc[m + 4][n], 0, 0, 0);
        #pragma unroll
        for (int m = 0; m < 4; m++)
            #pragma unroll
            for (int n = 0; n < NF; n++)
                acc[m + 4][n] = __builtin_amdgcn_mfma_f32_16x16x32_bf16(ag[m][1], bf[n][1], acc[m + 4][n], 0, 0, 0);
        __builtin_amdgcn_s_setprio(0);
        // single sync point per tile: drain own stage loads, then barrier
        if (kt + 1 < NT) asm volatile("s_waitcnt vmcnt(0)" ::: "memory");
        FENCE; __builtin_amdgcn_s_barrier(); FENCE;
    }

    const int rq = (lane >> 4) * 4;
    #pragma unroll
    for (int m = 0; m < 8; m++) {
        #pragma unroll
        for (int n = 0; n < NF; n++) {
            long row0 = m0 + wr * 128 + m * 16 + rq;
            long col = n0 + wc * (NF * 16) + n * 16 + r15;
            if (MODE == 0) {
                float* Cf = (float*)C0;
                #pragma unroll
                for (int i = 0; i < 4; i++) Cf[(row0 + i) * N + col] = acc[m][n][i];
            } else { // MODE 3: per-fragment routing (16-wide frags never straddle x1024 bounds)
                if (col < 4096) {
                    u16* Cb = (u16*)C0;
                    #pragma unroll
                    for (int i = 0; i < 4; i++) Cb[(row0 + i) * 4096 + col] = f2bf(acc[m][n][i]);
                } else if (col < 5120) {
                    u16* Cb = (u16*)C1;
                    long cl = col - 4096;
                    #pragma unroll
                    for (int i = 0; i < 4; i++) Cb[(row0 + i) * 1024 + cl] = f2bf(acc[m][n][i]);
                } else {
                    u16* Cb = (u16*)C2;
                    long cl = col - 5120;
                    ushort4 pk;
                    pk.x = f2bf(acc[m][n][0]);
                    pk.y = f2bf(acc[m][n][1]);
                    pk.z = f2bf(acc[m][n][2]);
                    pk.w = f2bf(acc[m][n][3]);
                    *(ushort4*)&Cb[cl * Mm + row0] = pk;
                }
            }
        }
    }
}

// ---------------- fused RMSNorm + RoPE, bf16 in-place (K path only) ----------------
__global__ __launch_bounds__(256) void k_normrope(u16* __restrict__ buf,
                                                  const float* __restrict__ w, int NH, float oscale) {
    int row = blockIdx.x * 4 + (threadIdx.x >> 6);
    int lane = threadIdx.x & 63;
    long base = (long)row * 128;
    float x1 = bf2f(buf[base + lane]), x2 = bf2f(buf[base + lane + 64]);
    float ss = x1 * x1 + x2 * x2;
    #pragma unroll
    for (int m = 1; m < 64; m <<= 1) ss += __shfl_xor(ss, m);
    float r = rsqrtf(ss * (1.f / 128.f) + 1e-6f);
    float n1 = x1 * r * w[lane], n2 = x2 * r * w[lane + 64];
    int pos = (row / NH) % Ss;
    float invf = exp2f((float)lane * (-19.931568569324174f / 64.f));
    float ang = (float)pos * invf;
    float c = cosf(ang), sn = sinf(ang);
    buf[base + lane] = f2bf((n1 * c - n2 * sn) * oscale);
    buf[base + lane + 64] = f2bf((n2 * c + n1 * sn) * oscale);
}

// ---------------- flash attention, causal-PAIRED q-tiles + XCD-chunked grid ----------------
// Q-side RMSNorm+RoPE FUSED into the prologue: lane holds q-row chunks d=16c+hi5*8+j;
// lanes l, l+32 cover complementary halves -> one shfl_xor(32) completes the row sum;
// RoPE pairs (d, d+64) are chunks (c, c+4) within the same lane. Trig once per block.
__global__ __launch_bounds__(256, 2) void k_attn(const u16* __restrict__ Q, const u16* __restrict__ Kb,
                                                 const u16* __restrict__ Vg, u16* __restrict__ O,
                                                 const float* __restrict__ qw, float qscale) {
    __shared__ u16 KT[2][64 * 128];
    __shared__ u16 VT[2][128 * 64];
    int tid = threadIdx.x, lane = tid & 63, wid = tid >> 6;
    int d0 = blockIdx.x;
    int L = (d0 & 7) * 64 + (d0 >> 3);
    int pr = L & 31;               // 0..31
    int hk = (L >> 5) & 7;
    int b = L >> 8;
    int h = hk * 4 + wid;
    int q0a = pr * 32;
    int q0b = (63 - pr) * 32;
    int c31 = lane & 31, hi5 = lane >> 5;
    int kx16 = (c31 & 15) << 3;
    int kx8 = (c31 & 7) << 3;

    short8 qfa[8], qfb[8];
    {
        const u16* qra = Q + ((long)(b * Ss + q0a + c31) * NQ + h) * Dd + hi5 * 8;
        const u16* qrb = Q + ((long)(b * Ss + q0b + c31) * NQ + h) * Dd + hi5 * 8;
        #pragma unroll
        for (int c = 0; c < 8; c++) {
            qfa[c] = *(const short8*)(qra + c * 16);
            qfb[c] = *(const short8*)(qrb + c * 16);
        }
    }
    // fused RMSNorm + RoPE + qscale on the raw q fragments
    auto NORMQ = [&](short8 (&qf)[8], int q0) {
        float ss = 0.f;
        #pragma unroll
        for (int c = 0; c < 8; c++)
            #pragma unroll
            for (int j = 0; j < 8; j++) {
                float x = bf2f(((const u16*)&qf[c])[j]);
                ss += x * x;
            }
        ss += __shfl_xor(ss, 32);
        float rn = rsqrtf(ss * (1.f / 128.f) + 1e-6f);
        float pos = (float)(q0 + c31);
        #pragma unroll
        for (int c = 0; c < 4; c++) {
            #pragma unroll
            for (int j = 0; j < 8; j++) {
                int d64 = c * 16 + hi5 * 8 + j;
                float x1 = bf2f(((const u16*)&qf[c])[j]) * rn * qw[d64];
                float x2 = bf2f(((const u16*)&qf[c + 4])[j]) * rn * qw[d64 + 64];
                float ang = pos * exp2f((float)d64 * (-19.931568569324174f / 64.f));
                float cs = cosf(ang), sn = sinf(ang);
                ((u16*)&qf[c])[j]     = f2bf((x1 * cs - x2 * sn) * qscale);
                ((u16*)&qf[c + 4])[j] = f2bf((x2 * cs + x1 * sn) * qscale);
            }
        }
    };
    NORMQ(qfa, q0a);
    NORMQ(qfb, q0b);

    const u16* kg[4];
    const u16* vg[4];
    int i0 = wid * 4;
    #pragma unroll
    for (int ii = 0; ii < 4; ii++) {
        int i = i0 + ii;
        int r = i * 4 + (lane >> 4);
        kg[ii] = Kb + ((long)(b * Ss + r) * NKV + hk) * Dd + 8 * ((lane & 15) ^ (r & 15));
        int d = i * 8 + (lane >> 3);
        vg[ii] = Vg + (long)(hk * Dd + d) * Mm + (long)b * Ss + 8 * ((lane & 7) ^ (d & 7));
    }

    f32x16 oaa[4], oab[4];
    #pragma unroll
    for (int f = 0; f < 4; f++)
        #pragma unroll
        for (int r = 0; r < 16; r++) { oaa[f][r] = 0.f; oab[f][r] = 0.f; }
    float mra = -INFINITY, lra = 0.f, mrb = -INFINITY, lrb = 0.f;

    const long kadv = (long)64 * NKV * Dd;
    int nt = q0b / 64 + 1;
    int cur = 0;

    auto STEP = [&](int k0, int q0, const short8 (&qf)[8], f32x16 (&oa)[4],
                    float& mrun, float& lrun) {
        int ql = q0 + c31;
        int krow = k0 & 32;
        f32x16 st;
        #pragma unroll
        for (int r = 0; r < 16; r++) st[r] = 0.f;
        __builtin_amdgcn_s_setprio(1);
        #pragma unroll
        for (int c = 0; c < 8; c++) {
            short8 kf = *(const short8*)&KT[cur][(krow + c31) * 128 + ((c * 16 + hi5 * 8) ^ kx16)];
            st = __builtin_amdgcn_mfma_f32_32x32x16_bf16(kf, qf[c], st, 0, 0, 0);
        }
        __builtin_amdgcn_s_setprio(0);
        float p[16];
        if (k0 + 31 > q0) {
            #pragma unroll
            for (int r = 0; r < 16; r++) {
                int kidx = k0 + (r & 3) + 8 * (r >> 2) + 4 * hi5;
                p[r] = (kidx > ql) ? -INFINITY : st[r];
            }
        } else {
            #pragma unroll
            for (int r = 0; r < 16; r++) p[r] = st[r];
        }
        float pmax = p[0];
        #pragma unroll
        for (int r = 1; r < 16; r++) pmax = fmaxf(pmax, p[r]);
        pmax = fmaxf(pmax, __shfl_xor(pmax, 32));
        if (!__all(pmax - mrun <= 8.f)) {
            float mnew = fmaxf(mrun, pmax);
            float sc = __builtin_amdgcn_exp2f(mrun - mnew);
            lrun *= sc;
            #pragma unroll
            for (int f = 0; f < 4; f++)
                #pragma unroll
                for (int r = 0; r < 16; r++) oa[f][r] *= sc;
            mrun = mnew;
        }
        float ls = 0.f;
        #pragma unroll
        for (int r = 0; r < 16; r++) {
            float e = __builtin_amdgcn_exp2f(p[r] - mrun);
            p[r] = e;
            ls += e;
        }
        ls += __shfl_xor(ls, 32);
        lrun += ls;

        u32 w0 = cvtpk(p[0], p[1]), w1 = cvtpk(p[2], p[3]);
        u32 w2 = cvtpk(p[4], p[5]), w3 = cvtpk(p[6], p[7]);
        u32 w4 = cvtpk(p[8], p[9]), w5 = cvtpk(p[10], p[11]);
        u32 w6 = cvtpk(p[12], p[13]), w7 = cvtpk(p[14], p[15]);
        u32 x0 = (u32)__shfl_xor((int)w0, 32), x1 = (u32)__shfl_xor((int)w1, 32);
        u32 x2 = (u32)__shfl_xor((int)w2, 32), x3 = (u32)__shfl_xor((int)w3, 32);
        u32 x4 = (u32)__shfl_xor((int)w4, 32), x5 = (u32)__shfl_xor((int)w5, 32);
        u32 x6 = (u32)__shfl_xor((int)w6, 32), x7 = (u32)__shfl_xor((int)w7, 32);
        union { u32 u[4]; short8 s; } pb0, pb1;
        if (hi5) {
            pb0.u[0] = x2; pb0.u[1] = x3; pb0.u[2] = w2; pb0.u[3] = w3;
            pb1.u[0] = x6; pb1.u[1] = x7; pb1.u[2] = w6; pb1.u[3] = w7;
        } else {
            pb0.u[0] = w0; pb0.u[1] = w1; pb0.u[2] = x0; pb0.u[3] = x1;
            pb1.u[0] = w4; pb1.u[1] = w5; pb1.u[2] = x4; pb1.u[3] = x5;
        }
        __builtin_amdgcn_s_setprio(1);
        #pragma unroll
        for (int f = 0; f < 4; f++) {
            int d = 32 * f + c31;
            const u16* vrow = &VT[cur][d * 64];
            short8 v0 = *(const short8*)&vrow[(krow + hi5 * 8) ^ kx8];
            short8 v1 = *(const short8*)&vrow[(krow + 16 + hi5 * 8) ^ kx8];
            oa[f] = __builtin_amdgcn_mfma_f32_32x32x16_bf16(v0, pb0.s, oa[f], 0, 0, 0);
            oa[f] = __builtin_amdgcn_mfma_f32_32x32x16_bf16(v1, pb1.s, oa[f], 0, 0, 0);
        }
        __builtin_amdgcn_s_setprio(0);
    };

    #pragma unroll
    for (int ii = 0; ii < 4; ii++) {
        gld16(kg[ii], &KT[0][(i0 + ii) * 512]);
        gld16(vg[ii], &VT[0][(i0 + ii) * 512]);
    }
    __syncthreads();

    for (int t = 0; t < nt; ++t) {
        if (t + 1 < nt) {
            long ko = (long)(t + 1) * kadv;
            int vo = (t + 1) * 64;
            #pragma unroll
            for (int ii = 0; ii < 4; ii++) {
                gld16(kg[ii] + ko, &KT[cur ^ 1][(i0 + ii) * 512]);
                gld16(vg[ii] + vo, &VT[cur ^ 1][(i0 + ii) * 512]);
            }
        }
        #pragma unroll
        for (int ks = 0; ks < 2; ++ks) {
            int k0 = t * 64 + ks * 32;
            if (k0 <= q0a + 31) STEP(k0, q0a, qfa, oaa, mra, lra);
            if (k0 <= q0b + 31) STEP(k0, q0b, qfb, oab, mrb, lrb);
        }
        __syncthreads();
        cur ^= 1;
    }

    #pragma unroll
    for (int x = 0; x < 2; x++) {
        int q0 = x ? q0b : q0a;
        f32x16* oa = x ? oab : oaa;
        float linv = 1.f / (x ? lrb : lra);
        u16* orow = O + ((long)(b * Ss + q0 + c31) * NQ + h) * Dd;
        #pragma unroll
        for (int f = 0; f < 4; f++) {
            #pragma unroll
            for (int rq = 0; rq < 4; rq++) {
                int dbase = 32 * f + 8 * rq + 4 * hi5;
                union { u32 u[2]; ushort4 v; } pk;
                pk.u[0] = cvtpk(oa[f][4 * rq + 0] * linv, oa[f][4 * rq + 1] * linv);
                pk.u[1] = cvtpk(oa[f][4 * rq + 2] * linv, oa[f][4 * rq + 3] * linv);
                *(ushort4*)(orow + dbase) = pk.v;
            }
        }
    }
}

// ---------------- launch ----------------
// Workspace layout (128 MB):
//   [  0, 32M): xb    x bf16; dead after QKV GEMM -> reused as ao
//   [ 32, 80M): Wqkv  contiguous wq^T | wk^T | wv^T; dead after QKV GEMM -> wo^T reuses
//   [ 80,112M): qb   (raw q bf16; normrope applied inside k_attn)
//   [112,120M): kb   (normrope in-place)
//   [120,128M): vt
extern "C" void kernel_launch(void* const* d_in, const int* in_sizes, int n_in,
                              void* d_out, int out_size, void* d_ws, size_t ws_size,
                              hipStream_t stream) {
    (void)in_sizes; (void)n_in; (void)out_size; (void)ws_size;
    const float* x = (const float*)d_in[0];
    const float* wq = (const float*)d_in[1];
    const float* wk = (const float*)d_in[2];
    const float* wv = (const float*)d_in[3];
    const float* wo = (const float*)d_in[4];
    const float* qnw = (const float*)d_in[5];
    const float* knw = (const float*)d_in[6];

    char* ws = (char*)d_ws;
    const size_t MB = 1024 * 1024;
    const float qscale = (float)(0.08838834764831845 * 1.4426950408889634);

    u16* xb = (u16*)(ws);
    u16* Wqkv = (u16*)(ws + 32 * MB);
    u16* qb = (u16*)(ws + 80 * MB);
    u16* kb = (u16*)(ws + 112 * MB);
    u16* vt = (u16*)(ws + 120 * MB);
    u16* ao = xb;
    u16* WoT = Wqkv; // Wqkv dead after QKV GEMM

    int n4 = Mm * Hh / 4;
    k_cast<<<n4 / 256, 256, 0, stream>>>((const float4*)x, (ushort4*)xb, n4);

    // vectorized 64x64 transposes (float4 in / ushort4 out)
    k_transpose<<<dim3(Hh / 64, Hh / 64), 256, 0, stream>>>(wq, Wqkv, Hh, Hh);
    k_transpose<<<dim3((NKV * Dd) / 64, Hh / 64), 256, 0, stream>>>(wk, Wqkv + (size_t)4096 * Hh, Hh, NKV * Dd);
    k_transpose<<<dim3((NKV * Dd) / 64, Hh / 64), 256, 0, stream>>>(wv, Wqkv + (size_t)5120 * Hh, Hh, NKV * Dd);

    // fused QKV GEMM: 256x192 tiles, 512 blocks = 2 exact generations
    k_gemm256<3><<<32 * (Mm / 256), 512, 0, stream>>>(xb, Wqkv, qb, kb, vt, Mm, 6144, Hh, 32);

    // K normrope (standalone; Q normrope fused into k_attn)
    k_normrope<<<(Mm * NKV) / 4, 256, 0, stream>>>(kb, knw, NKV, 1.0f);

    // attention: paired q-tiles, XCD-chunked grid (512 blocks), fused Q-normrope
    k_attn<<<512, 256, 0, stream>>>(qb, kb, vt, ao, qnw, qscale);

    // output projection -> f32 d_out: 256x256 tiles, 256 blocks = 1 exact generation
    k_transpose<<<dim3(Hh / 64, Hh / 64), 256, 0, stream>>>(wo, WoT, Hh, Hh);
    k_gemm256<0><<<16 * (Mm / 256), 512, 0, stream>>>(ao, WoT, d_out, nullptr, nullptr, Mm, Hh, NQ * Dd, 16);
}

// Round 21
// 524.424 us; speedup vs baseline: 1.3166x; 1.3166x over previous
//
#include <hip/hip_runtime.h>
#include <hip/hip_bf16.h>

#define DEV __device__ __forceinline__

typedef unsigned short u16;
typedef unsigned int u32;
typedef __attribute__((ext_vector_type(8))) short short8;
typedef __attribute__((ext_vector_type(4))) float f32x4;
typedef __attribute__((ext_vector_type(16))) float f32x16;

static constexpr int Bb = 2, Ss = 2048, Hh = 4096, NQ = 32, NKV = 8, Dd = 128;
static constexpr int Mm = Bb * Ss; // 4096

DEV u16 f2bf(float f) {
    u32 u = __float_as_uint(f);
    u32 r = (u + 0x7fffu + ((u >> 16) & 1u)) >> 16;
    return (u16)r;
}
DEV float bf2f(u16 b) { return __uint_as_float((u32)b << 16); }
DEV u32 cvtpk(float lo, float hi) { // dst.lo=bf16(lo), dst.hi=bf16(hi)
    u32 r;
    asm("v_cvt_pk_bf16_f32 %0, %1, %2" : "=v"(r) : "v"(lo), "v"(hi));
    return r;
}

// ---------------- elementwise f32 -> bf16 cast ----------------
__global__ void k_cast(const float4* __restrict__ in, ushort4* __restrict__ out, int n4) {
    int i = blockIdx.x * 256 + threadIdx.x;
    if (i < n4) {
        float4 v = in[i];
        ushort4 o;
        o.x = f2bf(v.x); o.y = f2bf(v.y); o.z = f2bf(v.z); o.w = f2bf(v.w);
        out[i] = o;
    }
}

// ---------------- transpose + cast: in (R,C) f32 -> out (C,R) bf16 ----------------
// 64x64 tile, 256 threads (16x16). float4 reads, bf16 into LDS transposed, ushort4 writes.
__global__ __launch_bounds__(256) void k_transpose(const float* __restrict__ in, u16* __restrict__ out,
                                                   int R, int C) {
    __shared__ u16 t[64][68];
    int tx = threadIdx.x & 15, ty = threadIdx.x >> 4; // 16 x 16
    long tr = (long)blockIdx.y * 64, tc = (long)blockIdx.x * 64;
    #pragma unroll
    for (int j = 0; j < 4; j++) {
        int r = ty + j * 16;
        float4 v = *(const float4*)&in[(tr + r) * C + tc + tx * 4];
        t[tx * 4 + 0][r] = f2bf(v.x);
        t[tx * 4 + 1][r] = f2bf(v.y);
        t[tx * 4 + 2][r] = f2bf(v.z);
        t[tx * 4 + 3][r] = f2bf(v.w);
    }
    __syncthreads();
    #pragma unroll
    for (int j = 0; j < 4; j++) {
        int c = ty + j * 16;
        *(ushort4*)&out[(tc + c) * R + tr + tx * 4] = *(ushort4*)&t[c][tx * 4];
    }
}

DEV void gld16(const void* g, void* l) {
    __builtin_amdgcn_global_load_lds((const __attribute__((address_space(1))) void*)g,
                                     (__attribute__((address_space(3))) void*)l, 16, 0, 0);
}

#define FENCE asm volatile("" ::: "memory")

// ---------------- 256xNW-tile 8-wave GEMM, minimum 2-phase K-loop ----------------
// ONE vmcnt(0) + ONE s_barrier per K-tile (round-16/18/19 proven best):
//   for kt: STAGE(kt+1 -> buf^1); reads+MFMA from buf; vmcnt(0); barrier.
// MODE 0: f32 C0 row-major (ld=N), N-tile 256 (NF=4) -> 256 blocks (1 generation).
// MODE 3: fused QKV, N-tile 192 (NF=3) -> 512 blocks (2 exact generations).
//   Per-FRAGMENT routing: col<4096 -> q C0 (ld 4096); col<5120 -> k C1 (ld 1024);
//   else v C2 TRANSPOSED (C2[(col-5120)*Mm + row]).
// LDS swizzle: 16B chunk c at row r holds global chunk c ^ (r&7); staging source
// pre-swizzled (linear gld16 dest), reads apply same xor -> conflict-free.
template <int MODE>
__global__ __launch_bounds__(512) void k_gemm256(const u16* __restrict__ A, const u16* __restrict__ B0,
                                                 void* __restrict__ C0, void* __restrict__ C1,
                                                 void* __restrict__ C2, int M, int N, int K, int nbx) {
    constexpr int NF = (MODE == 3) ? 3 : 4;     // n-frags per wave
    __shared__ u16 S[2][16384 + NF * 4096];
    const int tid = threadIdx.x, lane = tid & 63, wid = tid >> 6;
    const int wr = wid >> 2, wc = wid & 3;
    const int l = blockIdx.x;
    const int bx = l % nbx, by = l / nbx;
    const long m0 = (long)by * 256, n0 = (long)bx * (NF * 64);
    const int r15 = lane & 15;
    const int cch0 = 8 * ((lane >> 4) ^ (r15 & 7));

    const u16 *pA[4], *pB[NF];
    {
        int rl = lane >> 3;                      // row within 1KB issue
        int sc = 8 * ((lane & 7) ^ rl);          // pre-swizzled chunk
        #pragma unroll
        for (int j = 0; j < 4; j++)
            pA[j] = A + (m0 + (wid * 4 + j) * 8 + rl) * (long)K + sc;
        #pragma unroll
        for (int j = 0; j < NF; j++)
            pB[j] = B0 + (n0 + (wid * NF + j) * 8 + rl) * (long)K + sc;
    }

    f32x4 acc[8][NF];
    #pragma unroll
    for (int i = 0; i < 8; i++)
        #pragma unroll
        for (int j = 0; j < NF; j++) acc[i][j] = f32x4{0.f, 0.f, 0.f, 0.f};

    const int NT = K / 64;
    auto STAGE = [&](int t) {
        int tb = t & 1; long ko = (long)t * 64;
        #pragma unroll
        for (int j = 0; j < NF; j++) gld16(pB[j] + ko, (void*)&S[tb][16384 + (wid * NF + j) * 512]);
        #pragma unroll
        for (int j = 0; j < 4; j++) gld16(pA[j] + ko, (void*)&S[tb][(wid * 4 + j) * 512]);
    };

    const int aro = wr * 8192 + r15 * 64 + cch0;
    const int bro = 16384 + wc * (NF * 1024) + r15 * 64 + cch0;

    // prologue: stage tile 0, drain, sync
    STAGE(0);
    asm volatile("s_waitcnt vmcnt(0)" ::: "memory");
    FENCE; __builtin_amdgcn_s_barrier(); FENCE;

    short8 af[4][2], bf[NF][2];
    for (int kt = 0; kt < NT; ++kt) {
        const u16* Sb = S[kt & 1];
        // issue next-tile loads FIRST (they fly across this tile's compute)
        if (kt + 1 < NT) STAGE(kt + 1);
        // ---- reads B + A-mh0; MFMA (mh0 x all n)
        #pragma unroll
        for (int n = 0; n < NF; n++) {
            bf[n][0] = *(const short8*)&Sb[bro + n * 1024];
            bf[n][1] = *(const short8*)&Sb[(bro + n * 1024) ^ 32];
        }
        #pragma unroll
        for (int m = 0; m < 4; m++) {
            af[m][0] = *(const short8*)&Sb[aro + m * 1024];
            af[m][1] = *(const short8*)&Sb[(aro + m * 1024) ^ 32];
        }
        __builtin_amdgcn_s_setprio(1);
        #pragma unroll
        for (int m = 0; m < 4; m++)
            #pragma unroll
            for (int n = 0; n < NF; n++) {
                acc[m][n] = __builtin_amdgcn_mfma_f32_16x16x32_bf16(af[m][0], bf[n][0], acc[m][n], 0, 0, 0);
                acc[m][n] = __builtin_amdgcn_mfma_f32_16x16x32_bf16(af[m][1], bf[n][1], acc[m][n], 0, 0, 0);
            }
        __builtin_amdgcn_s_setprio(0);
        // ---- reads A-mh1; MFMA (mh1 x all n)
        short8 ag[4][2];
        #pragma unroll
        for (int m = 0; m < 4; m++) {
            ag[m][0] = *(const short8*)&Sb[aro + (m + 4) * 1024];
            ag[m][1] = *(const short8*)&Sb[(aro + (m + 4) * 1024) ^ 32];
        }
        __builtin_amdgcn_s_setprio(1);
        #pragma unroll
        for (int m = 0; m < 4; m++)
            #pragma unroll
            for (int n = 0; n < NF; n++) {
                acc[m + 4][n] = __builtin_amdgcn_mfma_f32_16x16x32_bf16(ag[m][0], bf[n][0], acc[m + 4][n], 0, 0, 0);
                acc[m + 4][n] = __builtin_amdgcn_mfma_f32_16x16x32_bf16(ag[m][1], bf[n][1], acc[m + 4][n], 0, 0, 0);
            }
        __builtin_amdgcn_s_setprio(0);
        // single sync point per tile: drain own stage loads, then barrier
        if (kt + 1 < NT) asm volatile("s_waitcnt vmcnt(0)" ::: "memory");
        FENCE; __builtin_amdgcn_s_barrier(); FENCE;
    }

    const int rq = (lane >> 4) * 4;
    #pragma unroll
    for (int m = 0; m < 8; m++) {
        #pragma unroll
        for (int n = 0; n < NF; n++) {
            long row0 = m0 + wr * 128 + m * 16 + rq;
            long col = n0 + wc * (NF * 16) + n * 16 + r15;
            if (MODE == 0) {
                float* Cf = (float*)C0;
                #pragma unroll
                for (int i = 0; i < 4; i++) Cf[(row0 + i) * N + col] = acc[m][n][i];
            } else { // MODE 3: per-fragment routing (16-wide frags never straddle x1024 bounds)
                if (col < 4096) {
                    u16* Cb = (u16*)C0;
                    #pragma unroll
                    for (int i = 0; i < 4; i++) Cb[(row0 + i) * 4096 + col] = f2bf(acc[m][n][i]);
                } else if (col < 5120) {
                    u16* Cb = (u16*)C1;
                    long cl = col - 4096;
                    #pragma unroll
                    for (int i = 0; i < 4; i++) Cb[(row0 + i) * 1024 + cl] = f2bf(acc[m][n][i]);
                } else {
                    u16* Cb = (u16*)C2;
                    long cl = col - 5120;
                    ushort4 pk;
                    pk.x = f2bf(acc[m][n][0]);
                    pk.y = f2bf(acc[m][n][1]);
                    pk.z = f2bf(acc[m][n][2]);
                    pk.w = f2bf(acc[m][n][3]);
                    *(ushort4*)&Cb[cl * Mm + row0] = pk;
                }
            }
        }
    }
}

// ---------------- fused RMSNorm + RoPE, bf16 in-place ----------------
__global__ __launch_bounds__(256) void k_normrope(u16* __restrict__ buf,
                                                  const float* __restrict__ w, int NH, float oscale) {
    int row = blockIdx.x * 4 + (threadIdx.x >> 6);
    int lane = threadIdx.x & 63;
    long base = (long)row * 128;
    float x1 = bf2f(buf[base + lane]), x2 = bf2f(buf[base + lane + 64]);
    float ss = x1 * x1 + x2 * x2;
    #pragma unroll
    for (int m = 1; m < 64; m <<= 1) ss += __shfl_xor(ss, m);
    float r = rsqrtf(ss * (1.f / 128.f) + 1e-6f);
    float n1 = x1 * r * w[lane], n2 = x2 * r * w[lane + 64];
    int pos = (row / NH) % Ss;
    float invf = exp2f((float)lane * (-19.931568569324174f / 64.f));
    float ang = (float)pos * invf;
    float c = cosf(ang), sn = sinf(ang);
    buf[base + lane] = f2bf((n1 * c - n2 * sn) * oscale);
    buf[base + lane + 64] = f2bf((n2 * c + n1 * sn) * oscale);
}

// ---------------- flash attention, causal-PAIRED q-tiles + XCD-chunked grid ----------------
__global__ __launch_bounds__(256, 2) void k_attn(const u16* __restrict__ Q, const u16* __restrict__ Kb,
                                                 const u16* __restrict__ Vg, u16* __restrict__ O) {
    __shared__ u16 KT[2][64 * 128];
    __shared__ u16 VT[2][128 * 64];
    int tid = threadIdx.x, lane = tid & 63, wid = tid >> 6;
    int d0 = blockIdx.x;
    int L = (d0 & 7) * 64 + (d0 >> 3);
    int pr = L & 31;               // 0..31
    int hk = (L >> 5) & 7;
    int b = L >> 8;
    int h = hk * 4 + wid;
    int q0a = pr * 32;
    int q0b = (63 - pr) * 32;
    int c31 = lane & 31, hi5 = lane >> 5;
    int kx16 = (c31 & 15) << 3;
    int kx8 = (c31 & 7) << 3;

    short8 qfa[8], qfb[8];
    {
        const u16* qra = Q + ((long)(b * Ss + q0a + c31) * NQ + h) * Dd + hi5 * 8;
        const u16* qrb = Q + ((long)(b * Ss + q0b + c31) * NQ + h) * Dd + hi5 * 8;
        #pragma unroll
        for (int c = 0; c < 8; c++) {
            qfa[c] = *(const short8*)(qra + c * 16);
            qfb[c] = *(const short8*)(qrb + c * 16);
        }
    }

    const u16* kg[4];
    const u16* vg[4];
    int i0 = wid * 4;
    #pragma unroll
    for (int ii = 0; ii < 4; ii++) {
        int i = i0 + ii;
        int r = i * 4 + (lane >> 4);
        kg[ii] = Kb + ((long)(b * Ss + r) * NKV + hk) * Dd + 8 * ((lane & 15) ^ (r & 15));
        int d = i * 8 + (lane >> 3);
        vg[ii] = Vg + (long)(hk * Dd + d) * Mm + (long)b * Ss + 8 * ((lane & 7) ^ (d & 7));
    }

    f32x16 oaa[4], oab[4];
    #pragma unroll
    for (int f = 0; f < 4; f++)
        #pragma unroll
        for (int r = 0; r < 16; r++) { oaa[f][r] = 0.f; oab[f][r] = 0.f; }
    float mra = -INFINITY, lra = 0.f, mrb = -INFINITY, lrb = 0.f;

    const long kadv = (long)64 * NKV * Dd;
    int nt = q0b / 64 + 1;
    int cur = 0;

    auto STEP = [&](int k0, int q0, const short8 (&qf)[8], f32x16 (&oa)[4],
                    float& mrun, float& lrun) {
        int ql = q0 + c31;
        int krow = k0 & 32;
        f32x16 st;
        #pragma unroll
        for (int r = 0; r < 16; r++) st[r] = 0.f;
        __builtin_amdgcn_s_setprio(1);
        #pragma unroll
        for (int c = 0; c < 8; c++) {
            short8 kf = *(const short8*)&KT[cur][(krow + c31) * 128 + ((c * 16 + hi5 * 8) ^ kx16)];
            st = __builtin_amdgcn_mfma_f32_32x32x16_bf16(kf, qf[c], st, 0, 0, 0);
        }
        __builtin_amdgcn_s_setprio(0);
        float p[16];
        if (k0 + 31 > q0) {
            #pragma unroll
            for (int r = 0; r < 16; r++) {
                int kidx = k0 + (r & 3) + 8 * (r >> 2) + 4 * hi5;
                p[r] = (kidx > ql) ? -INFINITY : st[r];
            }
        } else {
            #pragma unroll
            for (int r = 0; r < 16; r++) p[r] = st[r];
        }
        float pmax = p[0];
        #pragma unroll
        for (int r = 1; r < 16; r++) pmax = fmaxf(pmax, p[r]);
        pmax = fmaxf(pmax, __shfl_xor(pmax, 32));
        if (!__all(pmax - mrun <= 8.f)) {
            float mnew = fmaxf(mrun, pmax);
            float sc = __builtin_amdgcn_exp2f(mrun - mnew);
            lrun *= sc;
            #pragma unroll
            for (int f = 0; f < 4; f++)
                #pragma unroll
                for (int r = 0; r < 16; r++) oa[f][r] *= sc;
            mrun = mnew;
        }
        float ls = 0.f;
        #pragma unroll
        for (int r = 0; r < 16; r++) {
            float e = __builtin_amdgcn_exp2f(p[r] - mrun);
            p[r] = e;
            ls += e;
        }
        ls += __shfl_xor(ls, 32);
        lrun += ls;

        u32 w0 = cvtpk(p[0], p[1]), w1 = cvtpk(p[2], p[3]);
        u32 w2 = cvtpk(p[4], p[5]), w3 = cvtpk(p[6], p[7]);
        u32 w4 = cvtpk(p[8], p[9]), w5 = cvtpk(p[10], p[11]);
        u32 w6 = cvtpk(p[12], p[13]), w7 = cvtpk(p[14], p[15]);
        u32 x0 = (u32)__shfl_xor((int)w0, 32), x1 = (u32)__shfl_xor((int)w1, 32);
        u32 x2 = (u32)__shfl_xor((int)w2, 32), x3 = (u32)__shfl_xor((int)w3, 32);
        u32 x4 = (u32)__shfl_xor((int)w4, 32), x5 = (u32)__shfl_xor((int)w5, 32);
        u32 x6 = (u32)__shfl_xor((int)w6, 32), x7 = (u32)__shfl_xor((int)w7, 32);
        union { u32 u[4]; short8 s; } pb0, pb1;
        if (hi5) {
            pb0.u[0] = x2; pb0.u[1] = x3; pb0.u[2] = w2; pb0.u[3] = w3;
            pb1.u[0] = x6; pb1.u[1] = x7; pb1.u[2] = w6; pb1.u[3] = w7;
        } else {
            pb0.u[0] = w0; pb0.u[1] = w1; pb0.u[2] = x0; pb0.u[3] = x1;
            pb1.u[0] = w4; pb1.u[1] = w5; pb1.u[2] = x4; pb1.u[3] = x5;
        }
        __builtin_amdgcn_s_setprio(1);
        #pragma unroll
        for (int f = 0; f < 4; f++) {
            int d = 32 * f + c31;
            const u16* vrow = &VT[cur][d * 64];
            short8 v0 = *(const short8*)&vrow[(krow + hi5 * 8) ^ kx8];
            short8 v1 = *(const short8*)&vrow[(krow + 16 + hi5 * 8) ^ kx8];
            oa[f] = __builtin_amdgcn_mfma_f32_32x32x16_bf16(v0, pb0.s, oa[f], 0, 0, 0);
            oa[f] = __builtin_amdgcn_mfma_f32_32x32x16_bf16(v1, pb1.s, oa[f], 0, 0, 0);
        }
        __builtin_amdgcn_s_setprio(0);
    };

    #pragma unroll
    for (int ii = 0; ii < 4; ii++) {
        gld16(kg[ii], &KT[0][(i0 + ii) * 512]);
        gld16(vg[ii], &VT[0][(i0 + ii) * 512]);
    }
    __syncthreads();

    for (int t = 0; t < nt; ++t) {
        if (t + 1 < nt) {
            long ko = (long)(t + 1) * kadv;
            int vo = (t + 1) * 64;
            #pragma unroll
            for (int ii = 0; ii < 4; ii++) {
                gld16(kg[ii] + ko, &KT[cur ^ 1][(i0 + ii) * 512]);
                gld16(vg[ii] + vo, &VT[cur ^ 1][(i0 + ii) * 512]);
            }
        }
        #pragma unroll
        for (int ks = 0; ks < 2; ++ks) {
            int k0 = t * 64 + ks * 32;
            if (k0 <= q0a + 31) STEP(k0, q0a, qfa, oaa, mra, lra);
            if (k0 <= q0b + 31) STEP(k0, q0b, qfb, oab, mrb, lrb);
        }
        __syncthreads();
        cur ^= 1;
    }

    #pragma unroll
    for (int x = 0; x < 2; x++) {
        int q0 = x ? q0b : q0a;
        f32x16* oa = x ? oab : oaa;
        float linv = 1.f / (x ? lrb : lra);
        u16* orow = O + ((long)(b * Ss + q0 + c31) * NQ + h) * Dd;
        #pragma unroll
        for (int f = 0; f < 4; f++) {
            #pragma unroll
            for (int rq = 0; rq < 4; rq++) {
                int dbase = 32 * f + 8 * rq + 4 * hi5;
                union { u32 u[2]; ushort4 v; } pk;
                pk.u[0] = cvtpk(oa[f][4 * rq + 0] * linv, oa[f][4 * rq + 1] * linv);
                pk.u[1] = cvtpk(oa[f][4 * rq + 2] * linv, oa[f][4 * rq + 3] * linv);
                *(ushort4*)(orow + dbase) = pk.v;
            }
        }
    }
}

// ---------------- launch ----------------
// Workspace layout (128 MB):
//   [  0, 32M): xb    x bf16; dead after QKV GEMM -> reused as ao
//   [ 32, 80M): Wqkv  contiguous wq^T | wk^T | wv^T; dead after QKV GEMM -> wo^T reuses
//   [ 80,112M): qb   (normrope in-place)
//   [112,120M): kb   (normrope in-place)
//   [120,128M): vt
extern "C" void kernel_launch(void* const* d_in, const int* in_sizes, int n_in,
                              void* d_out, int out_size, void* d_ws, size_t ws_size,
                              hipStream_t stream) {
    (void)in_sizes; (void)n_in; (void)out_size; (void)ws_size;
    const float* x = (const float*)d_in[0];
    const float* wq = (const float*)d_in[1];
    const float* wk = (const float*)d_in[2];
    const float* wv = (const float*)d_in[3];
    const float* wo = (const float*)d_in[4];
    const float* qnw = (const float*)d_in[5];
    const float* knw = (const float*)d_in[6];

    char* ws = (char*)d_ws;
    const size_t MB = 1024 * 1024;
    const float qscale = (float)(0.08838834764831845 * 1.4426950408889634);

    u16* xb = (u16*)(ws);
    u16* Wqkv = (u16*)(ws + 32 * MB);
    u16* qb = (u16*)(ws + 80 * MB);
    u16* kb = (u16*)(ws + 112 * MB);
    u16* vt = (u16*)(ws + 120 * MB);
    u16* ao = xb;
    u16* WoT = Wqkv; // Wqkv dead after QKV GEMM

    int n4 = Mm * Hh / 4;
    k_cast<<<n4 / 256, 256, 0, stream>>>((const float4*)x, (ushort4*)xb, n4);

    // vectorized 64x64 transposes (float4 in / ushort4 out)
    k_transpose<<<dim3(Hh / 64, Hh / 64), 256, 0, stream>>>(wq, Wqkv, Hh, Hh);
    k_transpose<<<dim3((NKV * Dd) / 64, Hh / 64), 256, 0, stream>>>(wk, Wqkv + (size_t)4096 * Hh, Hh, NKV * Dd);
    k_transpose<<<dim3((NKV * Dd) / 64, Hh / 64), 256, 0, stream>>>(wv, Wqkv + (size_t)5120 * Hh, Hh, NKV * Dd);

    // fused QKV GEMM: 256x192 tiles, 512 blocks = 2 exact generations
    k_gemm256<3><<<32 * (Mm / 256), 512, 0, stream>>>(xb, Wqkv, qb, kb, vt, Mm, 6144, Hh, 32);

    k_normrope<<<(Mm * NQ) / 4, 256, 0, stream>>>(qb, qnw, NQ, qscale);
    k_normrope<<<(Mm * NKV) / 4, 256, 0, stream>>>(kb, knw, NKV, 1.0f);

    // attention: paired q-tiles, XCD-chunked grid (512 blocks)
    k_attn<<<512, 256, 0, stream>>>(qb, kb, vt, ao);

    // output projection -> f32 d_out: 256x256 tiles, 256 blocks = 1 exact generation
    k_transpose<<<dim3(Hh / 64, Hh / 64), 256, 0, stream>>>(wo, WoT, Hh, Hh);
    k_gemm256<0><<<16 * (Mm / 256), 512, 0, stream>>>(ao, WoT, d_out, nullptr, nullptr, Mm, Hh, NQ * Dd, 16);
}